// Round 15
// baseline (73.284 us; speedup 1.0000x reference)
//
#include <hip/hip_runtime.h>

#define NB 8
#define NO 2048
#define NQ 2048
#define ND 128
#define R  12        // Taylor terms for exp(x), x = tq*to/sigma^2 in [0,1] -> err ~ 6e-9
#define NCH 32       // o-chunks of 64 per batch

// NOTE: kernels BIT-IDENTICAL to round 11 (best known: 22.75 us).
// Probe: moment x1, out_kernel x5 (idempotent).
// dur = F + (D+Wm) + 5(D+Wo);  (dur - 22.75)/4 = D + Wo.  rocprof exposes out.

// ---------------- kernel 1: partial moment accumulation ----------------
__global__ __launch_bounds__(512) void moment_kernel(
    const float* __restrict__ obs_emb, const float* __restrict__ obs_times,
    const float* __restrict__ obs_mask, const float* __restrict__ log_sigma,
    float* __restrict__ Mpart, float* __restrict__ spart)
{
  __shared__ float Lacc[4 * R * ND];              // 24 KB
  __shared__ __align__(16) float coef_s[64 * R];  // 3 KB, row-major [o][n]
  const int tid   = threadIdx.x;
  const int d     = tid & 127;
  const int osub  = tid >> 7;          // 0..3, 16 o's each
  const int b     = blockIdx.x & 7;
  const int ch    = blockIdx.x >> 3;
  const int obase = ch * 64;

  const float ls     = log_sigma[0];
  const float inv_s2 = __expf(-2.0f * ls);   // 1/sigma^2
  const float kp     = 0.5f * inv_s2;

  if (tid < 64) {
    const float to = obs_times[b * NO + obase + tid];
    const float mk = obs_mask[b * NO + obase + tid];
    const float u  = to * inv_s2;
    const float inv_np1[R] = {1.f, 0.5f, 1.f/3.f, 0.25f, 0.2f, 1.f/6.f,
                              1.f/7.f, 0.125f, 1.f/9.f, 0.1f, 1.f/11.f, 1.f/12.f};
    float c = mk * __expf(-kp * to * to);
    #pragma unroll
    for (int n = 0; n < R; ++n) {
      coef_s[tid * R + n] = c;
      c *= u * inv_np1[n];
    }
  }
  __syncthreads();

  float acc[R];
  #pragma unroll
  for (int n = 0; n < R; ++n) acc[n] = 0.f;

  const float* eb = obs_emb + ((size_t)(b * NO + obase + osub * 16)) * ND + d;
  #pragma unroll 4
  for (int i = 0; i < 16; ++i) {
    const float ev = eb[(size_t)i * ND];
    const float4* cf = reinterpret_cast<const float4*>(coef_s + (osub * 16 + i) * R);
    const float4 c0 = cf[0], c1 = cf[1], c2 = cf[2];
    acc[0]  = fmaf(c0.x, ev, acc[0]);   acc[1]  = fmaf(c0.y, ev, acc[1]);
    acc[2]  = fmaf(c0.z, ev, acc[2]);   acc[3]  = fmaf(c0.w, ev, acc[3]);
    acc[4]  = fmaf(c1.x, ev, acc[4]);   acc[5]  = fmaf(c1.y, ev, acc[5]);
    acc[6]  = fmaf(c1.z, ev, acc[6]);   acc[7]  = fmaf(c1.w, ev, acc[7]);
    acc[8]  = fmaf(c2.x, ev, acc[8]);   acc[9]  = fmaf(c2.y, ev, acc[9]);
    acc[10] = fmaf(c2.z, ev, acc[10]);  acc[11] = fmaf(c2.w, ev, acc[11]);
  }

  #pragma unroll
  for (int n = 0; n < R; ++n) Lacc[(osub * R + n) * ND + d] = acc[n];
  __syncthreads();

  float* Mout = Mpart + ((size_t)(b * NCH + ch)) * (R * ND);
  #pragma unroll
  for (int k = 0; k < 3; ++k) {
    const int e = k * 512 + tid;       // flat n*ND+d
    Mout[e] = (Lacc[e] + Lacc[1536 + e]) + (Lacc[3072 + e] + Lacc[4608 + e]);
  }
  if (tid < R) {
    float v = 0.f;
    #pragma unroll
    for (int o = 0; o < 64; ++o) v += coef_s[o * R + tid];
    spart[(b * NCH + ch) * R + tid] = v;
  }
}

// ---------------- kernel 2: reduce + fold W + emit ----------------
__global__ __launch_bounds__(512) void out_kernel(
    const float* __restrict__ query_times, const float* __restrict__ W_proj,
    const float* __restrict__ b_proj, const float* __restrict__ Mpart,
    const float* __restrict__ spart, float* __restrict__ out)
{
  __shared__ float Ml[R * ND];        // 6 KB
  __shared__ float Pl[8 * 196];       // 6.3 KB
  __shared__ float slb[R];
  const int tid = threadIdx.x;
  const int b   = blockIdx.x & 7;
  const int q0  = (blockIdx.x >> 3) * 64;

  {
    const float* Mp = Mpart + (size_t)b * NCH * (R * ND);
    #pragma unroll
    for (int k = 0; k < 3; ++k) {
      const int e = k * 512 + tid;
      float v0 = 0.f, v1 = 0.f, v2 = 0.f, v3 = 0.f;
      #pragma unroll
      for (int chh = 0; chh < NCH; chh += 4) {
        v0 += Mp[(chh + 0) * (R * ND) + e];
        v1 += Mp[(chh + 1) * (R * ND) + e];
        v2 += Mp[(chh + 2) * (R * ND) + e];
        v3 += Mp[(chh + 3) * (R * ND) + e];
      }
      Ml[e] = (v0 + v1) + (v2 + v3);
    }
    if (tid < R) {
      const float* sp = spart + b * NCH * R;
      float v = 0.f;
      #pragma unroll
      for (int chh = 0; chh < NCH; ++chh) v += sp[chh * R + tid];
      slb[tid] = v;
    }
  }
  __syncthreads();

  {
    const int e  = tid >> 2;
    const int nh = (tid & 3) * 3;
    const float4* Wr = reinterpret_cast<const float4*>(W_proj) + e * 32;
    const float4* M4 = reinterpret_cast<const float4*>(Ml);
    float p0 = 0.f, p1 = 0.f, p2 = 0.f;
    #pragma unroll 8
    for (int d4 = 0; d4 < 32; ++d4) {
      const float4 w  = Wr[d4];
      const float4 m0 = M4[(nh + 0) * 32 + d4];
      const float4 m1 = M4[(nh + 1) * 32 + d4];
      const float4 m2 = M4[(nh + 2) * 32 + d4];
      p0 = fmaf(w.x, m0.x, fmaf(w.y, m0.y, fmaf(w.z, m0.z, fmaf(w.w, m0.w, p0))));
      p1 = fmaf(w.x, m1.x, fmaf(w.y, m1.y, fmaf(w.z, m1.z, fmaf(w.w, m1.w, p1))));
      p2 = fmaf(w.x, m2.x, fmaf(w.y, m2.y, fmaf(w.z, m2.z, fmaf(w.w, m2.w, p2))));
    }
    Pl[(e >> 4) * 196 + (nh + 0) * 16 + (e & 15)] = p0;
    Pl[(e >> 4) * 196 + (nh + 1) * 16 + (e & 15)] = p1;
    Pl[(e >> 4) * 196 + (nh + 2) * 16 + (e & 15)] = p2;
  }
  __syncthreads();

  {
    const int q  = q0 + (tid >> 3);
    const int eh = tid & 7;
    const float tq = query_times[b * NQ + q];

    float c[R];
    c[0] = 1.f;
    #pragma unroll
    for (int n = 1; n < R; ++n) c[n] = c[n - 1] * tq;
    float wsum = 0.f;
    #pragma unroll
    for (int n = 0; n < R; ++n) wsum = fmaf(c[n], slb[n], wsum);
    const float inv = 1.0f / fmaxf(wsum, 1e-8f);

    const float* Pe = Pl + eh * 196;
    float4 a0 = {0,0,0,0}, a1 = {0,0,0,0}, a2 = {0,0,0,0}, a3 = {0,0,0,0};
    #pragma unroll
    for (int n = 0; n < R; ++n) {
      const float cn = c[n];
      const float4 p0 = *reinterpret_cast<const float4*>(Pe + n * 16 + 0);
      const float4 p1 = *reinterpret_cast<const float4*>(Pe + n * 16 + 4);
      const float4 p2 = *reinterpret_cast<const float4*>(Pe + n * 16 + 8);
      const float4 p3 = *reinterpret_cast<const float4*>(Pe + n * 16 + 12);
      a0.x = fmaf(cn, p0.x, a0.x); a0.y = fmaf(cn, p0.y, a0.y);
      a0.z = fmaf(cn, p0.z, a0.z); a0.w = fmaf(cn, p0.w, a0.w);
      a1.x = fmaf(cn, p1.x, a1.x); a1.y = fmaf(cn, p1.y, a1.y);
      a1.z = fmaf(cn, p1.z, a1.z); a1.w = fmaf(cn, p1.w, a1.w);
      a2.x = fmaf(cn, p2.x, a2.x); a2.y = fmaf(cn, p2.y, a2.y);
      a2.z = fmaf(cn, p2.z, a2.z); a2.w = fmaf(cn, p2.w, a2.w);
      a3.x = fmaf(cn, p3.x, a3.x); a3.y = fmaf(cn, p3.y, a3.y);
      a3.z = fmaf(cn, p3.z, a3.z); a3.w = fmaf(cn, p3.w, a3.w);
    }
    const float4* B4 = reinterpret_cast<const float4*>(b_proj) + eh * 4;
    const float4 bb0 = B4[0], bb1 = B4[1], bb2 = B4[2], bb3 = B4[3];
    float4* orow = reinterpret_cast<float4*>(out + ((size_t)(b * NQ + q)) * ND + eh * 16);
    orow[0] = make_float4(fmaf(a0.x, inv, bb0.x), fmaf(a0.y, inv, bb0.y),
                          fmaf(a0.z, inv, bb0.z), fmaf(a0.w, inv, bb0.w));
    orow[1] = make_float4(fmaf(a1.x, inv, bb1.x), fmaf(a1.y, inv, bb1.y),
                          fmaf(a1.z, inv, bb1.z), fmaf(a1.w, inv, bb1.w));
    orow[2] = make_float4(fmaf(a2.x, inv, bb2.x), fmaf(a2.y, inv, bb2.y),
                          fmaf(a2.z, inv, bb2.z), fmaf(a2.w, inv, bb2.w));
    orow[3] = make_float4(fmaf(a3.x, inv, bb3.x), fmaf(a3.y, inv, bb3.y),
                          fmaf(a3.z, inv, bb3.z), fmaf(a3.w, inv, bb3.w));
  }
}

extern "C" void kernel_launch(void* const* d_in, const int* in_sizes, int n_in,
                              void* d_out, int out_size, void* d_ws, size_t ws_size,
                              hipStream_t stream) {
  const float* obs_emb     = (const float*)d_in[0];
  const float* obs_times   = (const float*)d_in[1];
  const float* query_times = (const float*)d_in[2];
  const float* obs_mask    = (const float*)d_in[3];
  const float* log_sigma   = (const float*)d_in[4];
  const float* W_proj      = (const float*)d_in[5];
  const float* b_proj      = (const float*)d_in[6];
  float* out = (float*)d_out;

  float* Mpart = (float*)d_ws;                          // 8*32*12*128 f32 = 1.57 MB
  float* spart = Mpart + (size_t)NB * NCH * R * ND;     // 8*32*12

  moment_kernel<<<NB * NCH, 512, 0, stream>>>(obs_emb, obs_times, obs_mask,
                                              log_sigma, Mpart, spart);
  // Asymmetric differencing probe: out x5 (idempotent) -> rocprof-visible.
  for (int rep = 0; rep < 5; ++rep)
    out_kernel<<<NB * (NQ / 64), 512, 0, stream>>>(query_times, W_proj, b_proj,
                                                   Mpart, spart, out);
}

// Round 16
// 22.462 us; speedup vs baseline: 3.2625x; 3.2625x over previous
//
#include <hip/hip_runtime.h>

#define NB 8
#define NO 2048
#define NQ 2048
#define ND 128
#define R  12        // Taylor terms for exp(x), x = tq*to/sigma^2 in [0,1] -> err ~ 6e-9
#define NCH 32       // o-chunks of 64 per batch

// ---------------- kernel 1: partial moment accumulation (R11 bit-identical) --
__global__ __launch_bounds__(512) void moment_kernel(
    const float* __restrict__ obs_emb, const float* __restrict__ obs_times,
    const float* __restrict__ obs_mask, const float* __restrict__ log_sigma,
    float* __restrict__ Mpart, float* __restrict__ spart)
{
  __shared__ float Lacc[4 * R * ND];              // 24 KB
  __shared__ __align__(16) float coef_s[64 * R];  // 3 KB, row-major [o][n]
  const int tid   = threadIdx.x;
  const int d     = tid & 127;
  const int osub  = tid >> 7;          // 0..3, 16 o's each
  const int b     = blockIdx.x & 7;
  const int ch    = blockIdx.x >> 3;
  const int obase = ch * 64;

  const float ls     = log_sigma[0];
  const float inv_s2 = __expf(-2.0f * ls);   // 1/sigma^2
  const float kp     = 0.5f * inv_s2;

  if (tid < 64) {
    const float to = obs_times[b * NO + obase + tid];
    const float mk = obs_mask[b * NO + obase + tid];
    const float u  = to * inv_s2;
    const float inv_np1[R] = {1.f, 0.5f, 1.f/3.f, 0.25f, 0.2f, 1.f/6.f,
                              1.f/7.f, 0.125f, 1.f/9.f, 0.1f, 1.f/11.f, 1.f/12.f};
    float c = mk * __expf(-kp * to * to);
    #pragma unroll
    for (int n = 0; n < R; ++n) {
      coef_s[tid * R + n] = c;
      c *= u * inv_np1[n];
    }
  }
  __syncthreads();

  float acc[R];
  #pragma unroll
  for (int n = 0; n < R; ++n) acc[n] = 0.f;

  const float* eb = obs_emb + ((size_t)(b * NO + obase + osub * 16)) * ND + d;
  #pragma unroll 4
  for (int i = 0; i < 16; ++i) {
    const float ev = eb[(size_t)i * ND];
    const float4* cf = reinterpret_cast<const float4*>(coef_s + (osub * 16 + i) * R);
    const float4 c0 = cf[0], c1 = cf[1], c2 = cf[2];
    acc[0]  = fmaf(c0.x, ev, acc[0]);   acc[1]  = fmaf(c0.y, ev, acc[1]);
    acc[2]  = fmaf(c0.z, ev, acc[2]);   acc[3]  = fmaf(c0.w, ev, acc[3]);
    acc[4]  = fmaf(c1.x, ev, acc[4]);   acc[5]  = fmaf(c1.y, ev, acc[5]);
    acc[6]  = fmaf(c1.z, ev, acc[6]);   acc[7]  = fmaf(c1.w, ev, acc[7]);
    acc[8]  = fmaf(c2.x, ev, acc[8]);   acc[9]  = fmaf(c2.y, ev, acc[9]);
    acc[10] = fmaf(c2.z, ev, acc[10]);  acc[11] = fmaf(c2.w, ev, acc[11]);
  }

  #pragma unroll
  for (int n = 0; n < R; ++n) Lacc[(osub * R + n) * ND + d] = acc[n];
  __syncthreads();

  float* Mout = Mpart + ((size_t)(b * NCH + ch)) * (R * ND);
  #pragma unroll
  for (int k = 0; k < 3; ++k) {
    const int e = k * 512 + tid;       // flat n*ND+d
    Mout[e] = (Lacc[e] + Lacc[1536 + e]) + (Lacc[3072 + e] + Lacc[4608 + e]);
  }
  if (tid < R) {
    float v = 0.f;
    #pragma unroll
    for (int o = 0; o < 64; ++o) v += coef_s[o * R + tid];
    spart[(b * NCH + ch) * R + tid] = v;
  }
}

// ---------------- kernel 2: per-batch reduce + fold W ----------------
__global__ __launch_bounds__(512) void mid_kernel(
    const float* __restrict__ W_proj, const float* __restrict__ Mpart,
    const float* __restrict__ spart, float* __restrict__ Pg, float* __restrict__ sg)
{
  __shared__ float Ml[R * ND];   // 6 KB
  const int tid = threadIdx.x;
  const int b   = blockIdx.x;

  const float* Mp = Mpart + (size_t)b * NCH * (R * ND);
  #pragma unroll
  for (int k = 0; k < 3; ++k) {
    const int e = k * 512 + tid;
    float v0 = 0.f, v1 = 0.f, v2 = 0.f, v3 = 0.f;
    #pragma unroll
    for (int ch = 0; ch < NCH; ch += 4) {
      v0 += Mp[(ch + 0) * (R * ND) + e];
      v1 += Mp[(ch + 1) * (R * ND) + e];
      v2 += Mp[(ch + 2) * (R * ND) + e];
      v3 += Mp[(ch + 3) * (R * ND) + e];
    }
    Ml[e] = (v0 + v1) + (v2 + v3);
  }
  if (tid < R) {
    const float* sp = spart + b * NCH * R;
    float v = 0.f;
    #pragma unroll
    for (int ch = 0; ch < NCH; ++ch) v += sp[ch * R + tid];
    sg[b * R + tid] = v;
  }
  __syncthreads();

  const int e  = tid >> 2;
  const int nh = (tid & 3) * 3;
  const float4* Wr = reinterpret_cast<const float4*>(W_proj) + e * 32;
  const float4* M4 = reinterpret_cast<const float4*>(Ml);
  float p0 = 0.f, p1 = 0.f, p2 = 0.f;
  #pragma unroll 8
  for (int d4 = 0; d4 < 32; ++d4) {
    const float4 w  = Wr[d4];
    const float4 m0 = M4[(nh + 0) * 32 + d4];
    const float4 m1 = M4[(nh + 1) * 32 + d4];
    const float4 m2 = M4[(nh + 2) * 32 + d4];
    p0 = fmaf(w.x, m0.x, fmaf(w.y, m0.y, fmaf(w.z, m0.z, fmaf(w.w, m0.w, p0))));
    p1 = fmaf(w.x, m1.x, fmaf(w.y, m1.y, fmaf(w.z, m1.z, fmaf(w.w, m1.w, p1))));
    p2 = fmaf(w.x, m2.x, fmaf(w.y, m2.y, fmaf(w.z, m2.z, fmaf(w.w, m2.w, p2))));
  }
  float* Pb = Pg + (size_t)b * (R * ND);
  Pb[(nh + 0) * ND + e] = p0;
  Pb[(nh + 1) * ND + e] = p1;
  Pb[(nh + 2) * ND + e] = p2;
}

// ---------------- kernel 3: emit (fill-kernel shape) ----------------
// grid 2048 = 8 b x 256 q-tiles(8 q); block 256 (4 waves) -> 8 blocks/CU, 100% occ.
// thread: q = q0 + tid>>5, e = (tid&31)*4.  One float4 store per thread.
__global__ __launch_bounds__(256) void emit_kernel(
    const float* __restrict__ query_times, const float* __restrict__ b_proj,
    const float* __restrict__ Pg, const float* __restrict__ sg,
    float* __restrict__ out)
{
  __shared__ __align__(16) float Pl[R * ND];   // 6 KB, plain [n][e]
  __shared__ float sl[R];
  const int tid = threadIdx.x;
  const int b   = blockIdx.x & 7;
  const int q0  = (blockIdx.x >> 3) * 8;

  {
    const float4* Pb4 = reinterpret_cast<const float4*>(Pg + (size_t)b * (R * ND));
    float4* Pl4 = reinterpret_cast<float4*>(Pl);
    Pl4[tid] = Pb4[tid];
    if (tid < 128) Pl4[256 + tid] = Pb4[256 + tid];
    if (tid < R) sl[tid] = sg[b * R + tid];
  }
  __syncthreads();

  const int q  = q0 + (tid >> 5);
  const int ej = tid & 31;                 // e = ej*4
  const float tq = query_times[b * NQ + q];

  float c[R];
  c[0] = 1.f;
  #pragma unroll
  for (int n = 1; n < R; ++n) c[n] = c[n - 1] * tq;
  float wsum = 0.f;
  #pragma unroll
  for (int n = 0; n < R; ++n) wsum = fmaf(c[n], sl[n], wsum);
  const float inv = 1.0f / fmaxf(wsum, 1e-8f);

  const float4* Pl4 = reinterpret_cast<const float4*>(Pl);
  float4 a = {0.f, 0.f, 0.f, 0.f};
  #pragma unroll
  for (int n = 0; n < R; ++n) {
    const float cn = c[n];
    const float4 p = Pl4[n * 32 + ej];
    a.x = fmaf(cn, p.x, a.x); a.y = fmaf(cn, p.y, a.y);
    a.z = fmaf(cn, p.z, a.z); a.w = fmaf(cn, p.w, a.w);
  }
  const float4 bb = reinterpret_cast<const float4*>(b_proj)[ej];
  reinterpret_cast<float4*>(out + ((size_t)(b * NQ + q)) * ND)[ej] =
      make_float4(fmaf(a.x, inv, bb.x), fmaf(a.y, inv, bb.y),
                  fmaf(a.z, inv, bb.z), fmaf(a.w, inv, bb.w));
}

extern "C" void kernel_launch(void* const* d_in, const int* in_sizes, int n_in,
                              void* d_out, int out_size, void* d_ws, size_t ws_size,
                              hipStream_t stream) {
  const float* obs_emb     = (const float*)d_in[0];
  const float* obs_times   = (const float*)d_in[1];
  const float* query_times = (const float*)d_in[2];
  const float* obs_mask    = (const float*)d_in[3];
  const float* log_sigma   = (const float*)d_in[4];
  const float* W_proj      = (const float*)d_in[5];
  const float* b_proj      = (const float*)d_in[6];
  float* out = (float*)d_out;

  float* Mpart = (float*)d_ws;                          // 8*32*12*128 f32 = 1.57 MB
  float* spart = Mpart + (size_t)NB * NCH * R * ND;     // 8*32*12
  float* Pg    = spart + NB * NCH * R;                  // 8*12*128
  float* sg    = Pg + NB * R * ND;                      // 8*12

  moment_kernel<<<NB * NCH, 512, 0, stream>>>(obs_emb, obs_times, obs_mask,
                                              log_sigma, Mpart, spart);
  mid_kernel<<<NB, 512, 0, stream>>>(W_proj, Mpart, spart, Pg, sg);
  emit_kernel<<<NB * 256, 256, 0, stream>>>(query_times, b_proj, Pg, sg, out);
}

// Round 17
// 22.241 us; speedup vs baseline: 3.2950x; 1.0100x over previous
//
#include <hip/hip_runtime.h>

#define NB 8
#define NO 2048
#define NQ 2048
#define ND 128
#define R  12        // Taylor terms for exp(x), x = tq*to/sigma^2 in [0,1] -> err ~ 6e-9
#define NCH 32       // o-chunks of 64 per batch

typedef float f32x4_nt __attribute__((ext_vector_type(4)));

// ---------------- kernel 1: partial moment accumulation (R11 bit-identical) --
__global__ __launch_bounds__(512) void moment_kernel(
    const float* __restrict__ obs_emb, const float* __restrict__ obs_times,
    const float* __restrict__ obs_mask, const float* __restrict__ log_sigma,
    float* __restrict__ Mpart, float* __restrict__ spart)
{
  __shared__ float Lacc[4 * R * ND];              // 24 KB
  __shared__ __align__(16) float coef_s[64 * R];  // 3 KB, row-major [o][n]
  const int tid   = threadIdx.x;
  const int d     = tid & 127;
  const int osub  = tid >> 7;          // 0..3, 16 o's each
  const int b     = blockIdx.x & 7;
  const int ch    = blockIdx.x >> 3;
  const int obase = ch * 64;

  const float ls     = log_sigma[0];
  const float inv_s2 = __expf(-2.0f * ls);   // 1/sigma^2
  const float kp     = 0.5f * inv_s2;

  if (tid < 64) {
    const float to = obs_times[b * NO + obase + tid];
    const float mk = obs_mask[b * NO + obase + tid];
    const float u  = to * inv_s2;
    const float inv_np1[R] = {1.f, 0.5f, 1.f/3.f, 0.25f, 0.2f, 1.f/6.f,
                              1.f/7.f, 0.125f, 1.f/9.f, 0.1f, 1.f/11.f, 1.f/12.f};
    float c = mk * __expf(-kp * to * to);
    #pragma unroll
    for (int n = 0; n < R; ++n) {
      coef_s[tid * R + n] = c;
      c *= u * inv_np1[n];
    }
  }
  __syncthreads();

  float acc[R];
  #pragma unroll
  for (int n = 0; n < R; ++n) acc[n] = 0.f;

  const float* eb = obs_emb + ((size_t)(b * NO + obase + osub * 16)) * ND + d;
  #pragma unroll 4
  for (int i = 0; i < 16; ++i) {
    const float ev = eb[(size_t)i * ND];
    const float4* cf = reinterpret_cast<const float4*>(coef_s + (osub * 16 + i) * R);
    const float4 c0 = cf[0], c1 = cf[1], c2 = cf[2];
    acc[0]  = fmaf(c0.x, ev, acc[0]);   acc[1]  = fmaf(c0.y, ev, acc[1]);
    acc[2]  = fmaf(c0.z, ev, acc[2]);   acc[3]  = fmaf(c0.w, ev, acc[3]);
    acc[4]  = fmaf(c1.x, ev, acc[4]);   acc[5]  = fmaf(c1.y, ev, acc[5]);
    acc[6]  = fmaf(c1.z, ev, acc[6]);   acc[7]  = fmaf(c1.w, ev, acc[7]);
    acc[8]  = fmaf(c2.x, ev, acc[8]);   acc[9]  = fmaf(c2.y, ev, acc[9]);
    acc[10] = fmaf(c2.z, ev, acc[10]);  acc[11] = fmaf(c2.w, ev, acc[11]);
  }

  #pragma unroll
  for (int n = 0; n < R; ++n) Lacc[(osub * R + n) * ND + d] = acc[n];
  __syncthreads();

  float* Mout = Mpart + ((size_t)(b * NCH + ch)) * (R * ND);
  #pragma unroll
  for (int k = 0; k < 3; ++k) {
    const int e = k * 512 + tid;       // flat n*ND+d
    Mout[e] = (Lacc[e] + Lacc[1536 + e]) + (Lacc[3072 + e] + Lacc[4608 + e]);
  }
  if (tid < R) {
    float v = 0.f;
    #pragma unroll
    for (int o = 0; o < 64; ++o) v += coef_s[o * R + tid];
    spart[(b * NCH + ch) * R + tid] = v;
  }
}

// ---------------- kernel 2: per-batch reduce + fold W ----------------
__global__ __launch_bounds__(512) void mid_kernel(
    const float* __restrict__ W_proj, const float* __restrict__ Mpart,
    const float* __restrict__ spart, float* __restrict__ Pg, float* __restrict__ sg)
{
  __shared__ float Ml[R * ND];   // 6 KB
  const int tid = threadIdx.x;
  const int b   = blockIdx.x;

  const float* Mp = Mpart + (size_t)b * NCH * (R * ND);
  #pragma unroll
  for (int k = 0; k < 3; ++k) {
    const int e = k * 512 + tid;
    float v0 = 0.f, v1 = 0.f, v2 = 0.f, v3 = 0.f;
    #pragma unroll
    for (int ch = 0; ch < NCH; ch += 4) {
      v0 += Mp[(ch + 0) * (R * ND) + e];
      v1 += Mp[(ch + 1) * (R * ND) + e];
      v2 += Mp[(ch + 2) * (R * ND) + e];
      v3 += Mp[(ch + 3) * (R * ND) + e];
    }
    Ml[e] = (v0 + v1) + (v2 + v3);
  }
  if (tid < R) {
    const float* sp = spart + b * NCH * R;
    float v = 0.f;
    #pragma unroll
    for (int ch = 0; ch < NCH; ++ch) v += sp[ch * R + tid];
    sg[b * R + tid] = v;
  }
  __syncthreads();

  const int e  = tid >> 2;
  const int nh = (tid & 3) * 3;
  const float4* Wr = reinterpret_cast<const float4*>(W_proj) + e * 32;
  const float4* M4 = reinterpret_cast<const float4*>(Ml);
  float p0 = 0.f, p1 = 0.f, p2 = 0.f;
  #pragma unroll 8
  for (int d4 = 0; d4 < 32; ++d4) {
    const float4 w  = Wr[d4];
    const float4 m0 = M4[(nh + 0) * 32 + d4];
    const float4 m1 = M4[(nh + 1) * 32 + d4];
    const float4 m2 = M4[(nh + 2) * 32 + d4];
    p0 = fmaf(w.x, m0.x, fmaf(w.y, m0.y, fmaf(w.z, m0.z, fmaf(w.w, m0.w, p0))));
    p1 = fmaf(w.x, m1.x, fmaf(w.y, m1.y, fmaf(w.z, m1.z, fmaf(w.w, m1.w, p1))));
    p2 = fmaf(w.x, m2.x, fmaf(w.y, m2.y, fmaf(w.z, m2.z, fmaf(w.w, m2.w, p2))));
  }
  float* Pb = Pg + (size_t)b * (R * ND);
  Pb[(nh + 0) * ND + e] = p0;
  Pb[(nh + 1) * ND + e] = p1;
  Pb[(nh + 2) * ND + e] = p2;
}

// ---------------- kernel 3: emit (fill shape + NON-TEMPORAL d_out stores) ----
// grid 2048 = 8 b x 256 q-tiles(8 q); block 256.  NT store leaves L2 clean ->
// no dirty-writeback attached to the terminal dispatch (theory under test).
__global__ __launch_bounds__(256) void emit_kernel(
    const float* __restrict__ query_times, const float* __restrict__ b_proj,
    const float* __restrict__ Pg, const float* __restrict__ sg,
    float* __restrict__ out)
{
  __shared__ __align__(16) float Pl[R * ND];   // 6 KB, plain [n][e]
  __shared__ float sl[R];
  const int tid = threadIdx.x;
  const int b   = blockIdx.x & 7;
  const int q0  = (blockIdx.x >> 3) * 8;

  {
    const float4* Pb4 = reinterpret_cast<const float4*>(Pg + (size_t)b * (R * ND));
    float4* Pl4 = reinterpret_cast<float4*>(Pl);
    Pl4[tid] = Pb4[tid];
    if (tid < 128) Pl4[256 + tid] = Pb4[256 + tid];
    if (tid < R) sl[tid] = sg[b * R + tid];
  }
  __syncthreads();

  const int q  = q0 + (tid >> 5);
  const int ej = tid & 31;                 // e = ej*4
  const float tq = query_times[b * NQ + q];

  float c[R];
  c[0] = 1.f;
  #pragma unroll
  for (int n = 1; n < R; ++n) c[n] = c[n - 1] * tq;
  float wsum = 0.f;
  #pragma unroll
  for (int n = 0; n < R; ++n) wsum = fmaf(c[n], sl[n], wsum);
  const float inv = 1.0f / fmaxf(wsum, 1e-8f);

  const float4* Pl4 = reinterpret_cast<const float4*>(Pl);
  float4 a = {0.f, 0.f, 0.f, 0.f};
  #pragma unroll
  for (int n = 0; n < R; ++n) {
    const float cn = c[n];
    const float4 p = Pl4[n * 32 + ej];
    a.x = fmaf(cn, p.x, a.x); a.y = fmaf(cn, p.y, a.y);
    a.z = fmaf(cn, p.z, a.z); a.w = fmaf(cn, p.w, a.w);
  }
  const float4 bb = reinterpret_cast<const float4*>(b_proj)[ej];
  f32x4_nt v;
  v.x = fmaf(a.x, inv, bb.x);
  v.y = fmaf(a.y, inv, bb.y);
  v.z = fmaf(a.z, inv, bb.z);
  v.w = fmaf(a.w, inv, bb.w);
  f32x4_nt* dst = reinterpret_cast<f32x4_nt*>(out + ((size_t)(b * NQ + q)) * ND) + ej;
  __builtin_nontemporal_store(v, dst);
}

extern "C" void kernel_launch(void* const* d_in, const int* in_sizes, int n_in,
                              void* d_out, int out_size, void* d_ws, size_t ws_size,
                              hipStream_t stream) {
  const float* obs_emb     = (const float*)d_in[0];
  const float* obs_times   = (const float*)d_in[1];
  const float* query_times = (const float*)d_in[2];
  const float* obs_mask    = (const float*)d_in[3];
  const float* log_sigma   = (const float*)d_in[4];
  const float* W_proj      = (const float*)d_in[5];
  const float* b_proj      = (const float*)d_in[6];
  float* out = (float*)d_out;

  float* Mpart = (float*)d_ws;                          // 8*32*12*128 f32 = 1.57 MB
  float* spart = Mpart + (size_t)NB * NCH * R * ND;     // 8*32*12
  float* Pg    = spart + NB * NCH * R;                  // 8*12*128
  float* sg    = Pg + NB * R * ND;                      // 8*12

  moment_kernel<<<NB * NCH, 512, 0, stream>>>(obs_emb, obs_times, obs_mask,
                                              log_sigma, Mpart, spart);
  mid_kernel<<<NB, 512, 0, stream>>>(W_proj, Mpart, spart, Pg, sg);
  emit_kernel<<<NB * 256, 256, 0, stream>>>(query_times, b_proj, Pg, sg, out);
}